// Round 6
// baseline (332.955 us; speedup 1.0000x reference)
//
#include <hip/hip_runtime.h>

#define B_ 2
#define H_ 16
#define S_ 2048
#define D_ 64
#define BQ 128     // q-rows per block: 8 waves = 4 row-groups x 2 key-halves
#define BK 64
#define NQB (S_ / BQ)   // 16 q-blocks per (b,h)
#define NKT (S_ / BK)   // 32 key tiles max
#define LDSH 64    // halfs per LDS row (128B); 16B chunks XOR-swizzled by row&7
#define LOG2E 1.4426950408889634f
#define FIXM 10.0f // fixed softmax shift (log2 domain); cancels exactly in O = PV/l

#if __has_builtin(__builtin_amdgcn_exp2f)
#define EXP2F(x) __builtin_amdgcn_exp2f(x)
#else
#define EXP2F(x) __expf((x) * 0.6931471805599453f)
#endif

typedef _Float16 half8 __attribute__((ext_vector_type(8)));
typedef _Float16 half4 __attribute__((ext_vector_type(4)));
typedef __fp16   fp16x2 __attribute__((ext_vector_type(2)));  // cvt_pkrtz return type
typedef float floatx4 __attribute__((ext_vector_type(4)));

// LDS carve (bytes):
//   Kl  [2][64][64] half @ 0       (16384)   logical [buf][key][dim]
//   Vt  [2][64][64] half @ 16384   (16384)   logical [buf][dim][key]
//   lut [256] float @ 32768        (1024)
// Epilogue reuses [0,34304) as fp32 scratch: Ox[128][66] @0, Lx[128] @33792.
#define VT_OFF  16384
#define LUT_OFF 32768
#define OX_STR  66
#define LX_OFF  33792
#define SMEM_BYTES 34304

__global__ __launch_bounds__(512, 4)
void t5_attn_kernel(const float* __restrict__ qg_, const float* __restrict__ kg_,
                    const float* __restrict__ vg_, const float* __restrict__ bt,
                    const int* __restrict__ elen, float* __restrict__ outg_)
{
    __shared__ __align__(16) unsigned char smem[SMEM_BYTES];
    _Float16* KL = reinterpret_cast<_Float16*>(smem);            // [2][4096]
    _Float16* VT = reinterpret_cast<_Float16*>(smem + VT_OFF);   // [2][4096]
    float*   lut = reinterpret_cast<float*>(smem + LUT_OFF);     // [256]

    const int tid  = threadIdx.x;
    const int wave = tid >> 6;
    const int lane = tid & 63;
    const int quad = lane >> 4;
    const int t16  = lane & 15;
    const int t8   = t16 & 7;    // row parity for the chunk XOR swizzle
    const int wq   = wave >> 1;  // 0..3: q row-group (32 rows)
    const int kh   = wave & 1;   // 0/1: key half (32 keys) of each 64-key tile

    // XCD-aware remap (verified FETCH 100->20MB): all 16 q-blocks of one (b,h)
    // land on one XCD; dispatch pairs each CU with (b=0,b=1) blocks.
    const int f    = blockIdx.x + NQB * (blockIdx.y + H_ * blockIdx.z);
    const int qblk = (f >> 3) & 15;
    const int bh   = (f & 7) | ((f >> 7) << 3);
    const int h    = bh & 15;
    const int b    = bh >> 4;

    // ---- bias LUT with FIXM folded in: lut[n] = bt[bucket(n)][h]*log2e - FIXM
    if (tid < 256) {
        int n = tid;
        int bucket;
        if (n < 16) {
            bucket = n;
        } else {
            int vl = (int)(__log2f((float)n * 0.0625f) * 4.0f);
            bucket = 16 + (vl < 15 ? vl : 15);
        }
        lut[n] = bt[bucket * H_ + h] * LOG2E - FIXM;
    }
    // uniform-tile shifts: arg = sa - sh, sh = FIXM - bias*log2e
    const float sh_next = FIXM - bt[h] * LOG2E;           // all d<=0 (bucket 0)
    const float sh_far  = FIXM - bt[31 * H_ + h] * LOG2E; // all d>=216 (bucket 31)

    // robust event_length read (int32 vs int64 layouts; valid lengths >= 1)
    const int len = (elen[1] == 0) ? elen[2 * b] : elen[b];
    const int ntiles = (len + BK - 1) >> 6;  // keys beyond len give exp()=0 exactly

    const size_t bhoff = ((size_t)b * H_ + h) * (size_t)(S_ * D_);
    const float* qptr = qg_ + bhoff;
    const float* kptr = kg_ + bhoff;
    const float* vptr = vg_ + bhoff;
    float*       optr = outg_ + bhoff;

    // ---- Q fragments: 2 row-groups x 2 k-chunks, scaled by (1/8)*log2e.
    // Built in A-layout; used in the B slot (A/B lane-mappings coincide for
    // 16x16x32), so QK^T computes S^T = K.Q^T: C row=key, col=qrow.
    half8 qf[2][2];
    {
        const float qscale = 0.125f * LOG2E;
        #pragma unroll
        for (int rg = 0; rg < 2; ++rg) {
            const int row = qblk * BQ + wq * 32 + rg * 16 + t16;
            const float* qp = qptr + (size_t)row * D_ + quad * 8;
            #pragma unroll
            for (int c = 0; c < 2; ++c) {
                const float4* pq = reinterpret_cast<const float4*>(qp + c * 32);
                float4 x0 = pq[0], x1 = pq[1];
                half8 hv;
                hv[0] = (_Float16)(x0.x * qscale); hv[1] = (_Float16)(x0.y * qscale);
                hv[2] = (_Float16)(x0.z * qscale); hv[3] = (_Float16)(x0.w * qscale);
                hv[4] = (_Float16)(x1.x * qscale); hv[5] = (_Float16)(x1.y * qscale);
                hv[6] = (_Float16)(x1.z * qscale); hv[7] = (_Float16)(x1.w * qscale);
                qf[rg][c] = hv;
            }
        }
    }

    floatx4 acc[2][4];         // acc[rg][nb][r]: qrow rg*16+quad*4+r, dim nb*16+t16
    float l_[2];               // per-lane partial row-sum (this wave's key-half)
    #pragma unroll
    for (int rg = 0; rg < 2; ++rg) {
        #pragma unroll
        for (int nb = 0; nb < 4; ++nb) acc[rg][nb] = floatx4{0.f, 0.f, 0.f, 0.f};
        l_[rg] = 0.f;
    }

    const int i_lo = qblk * BQ + wq * 32;  // first q-row this wave owns

    // pack 4 fp32 -> half4 (RTZ, matches previous P path rounding)
    auto pack4 = [](const floatx4& v) -> half4 {
        fp16x2 lo = __builtin_amdgcn_cvt_pkrtz(v[0], v[1]);
        fp16x2 hi = __builtin_amdgcn_cvt_pkrtz(v[2], v[3]);
        half4 w;
        w[0] = (_Float16)lo[0]; w[1] = (_Float16)lo[1];
        w[2] = (_Float16)hi[0]; w[3] = (_Float16)hi[1];
        return w;
    };

    // ---- staging geometry (tile-invariant)
    const int krow = tid >> 3;                                       // K row staged
    const int kst  = krow * LDSH + (((tid & 7) ^ (krow & 7)) << 3);  // swizzled
    const int vst  = lane * LDSH + ((wave ^ (lane & 7)) << 3);       // swizzled
    const int c8w  = (tid & 7) << 3;

    // two in-flight staging register sets (tiles A=even, B=odd)
    float4 kfa0, kfa1, kfb0, kfb1;
    float  vfa[8], vfb[8];

    auto prefetchA = [&](int kt) {
        const int ktc = kt < NKT ? kt : NKT - 1;   // clamp: beyond-len tiles never computed
        const float4* pp = reinterpret_cast<const float4*>(
            kptr + (size_t)(ktc * BK + krow) * D_ + c8w);
        kfa0 = pp[0]; kfa1 = pp[1];
        const float* vb = vptr + (size_t)(ktc * BK + wave * 8) * D_ + lane;
        #pragma unroll
        for (int jj = 0; jj < 8; ++jj) vfa[jj] = vb[jj * D_];
    };
    auto prefetchB = [&](int kt) {
        const int ktc = kt < NKT ? kt : NKT - 1;
        const float4* pp = reinterpret_cast<const float4*>(
            kptr + (size_t)(ktc * BK + krow) * D_ + c8w);
        kfb0 = pp[0]; kfb1 = pp[1];
        const float* vb = vptr + (size_t)(ktc * BK + wave * 8) * D_ + lane;
        #pragma unroll
        for (int jj = 0; jj < 8; ++jj) vfb[jj] = vb[jj * D_];
    };
    auto stageA = [&]() {   // -> buf0
        half8 hv;
        hv[0]=(_Float16)kfa0.x; hv[1]=(_Float16)kfa0.y; hv[2]=(_Float16)kfa0.z; hv[3]=(_Float16)kfa0.w;
        hv[4]=(_Float16)kfa1.x; hv[5]=(_Float16)kfa1.y; hv[6]=(_Float16)kfa1.z; hv[7]=(_Float16)kfa1.w;
        *reinterpret_cast<half8*>(KL + kst) = hv;
        half8 vv;
        #pragma unroll
        for (int jj = 0; jj < 8; ++jj) vv[jj] = (_Float16)vfa[jj];
        *reinterpret_cast<half8*>(VT + vst) = vv;
    };
    auto stageB = [&]() {   // -> buf1
        half8 hv;
        hv[0]=(_Float16)kfb0.x; hv[1]=(_Float16)kfb0.y; hv[2]=(_Float16)kfb0.z; hv[3]=(_Float16)kfb0.w;
        hv[4]=(_Float16)kfb1.x; hv[5]=(_Float16)kfb1.y; hv[6]=(_Float16)kfb1.z; hv[7]=(_Float16)kfb1.w;
        *reinterpret_cast<half8*>(KL + 4096 + kst) = hv;
        half8 vv;
        #pragma unroll
        for (int jj = 0; jj < 8; ++jj) vv[jj] = (_Float16)vfb[jj];
        *reinterpret_cast<half8*>(VT + 4096 + vst) = vv;
    };

    // ---- per-tile compute pieces (buf base is compile-time 0/4096)
    auto qk_tile = [&](const int bufb, const floatx4& ci, floatx4 (&sa)[2][2]) {
        #pragma unroll
        for (int rg = 0; rg < 2; ++rg)
            #pragma unroll
            for (int nb = 0; nb < 2; ++nb) sa[rg][nb] = ci;
        __builtin_amdgcn_s_setprio(1);
        #pragma unroll
        for (int kc = 0; kc < 2; ++kc) {
            #pragma unroll
            for (int nb = 0; nb < 2; ++nb) {
                half8 af = *reinterpret_cast<const half8*>(
                    KL + bufb + (kh * 32 + nb * 16 + t16) * LDSH +
                    ((((kc << 2) | quad) ^ t8) << 3));
                sa[0][nb] = __builtin_amdgcn_mfma_f32_16x16x32_f16(af, qf[0][kc], sa[0][nb], 0, 0, 0);
                sa[1][nb] = __builtin_amdgcn_mfma_f32_16x16x32_f16(af, qf[1][kc], sa[1][nb], 0, 0, 0);
            }
        }
        __builtin_amdgcn_s_setprio(0);
    };
    auto vload = [&](const int bufb, half4 (&bv)[4][2]) {
        #pragma unroll
        for (int nb = 0; nb < 4; ++nb) {
            #pragma unroll
            for (int s = 0; s < 2; ++s) {
                bv[nb][s] = *reinterpret_cast<const half4*>(
                    VT + bufb + (nb * 16 + t16) * LDSH +
                    ((((kh << 2) | (s << 1) | (quad >> 1)) ^ t8) << 3) +
                    ((quad & 1) << 2));
            }
        }
    };
    auto bias_exp = [&](const int keybase, const bool un, const bool uf,
                        const bool domask, floatx4 (&sa)[2][2]) {
        if (!un && !uf) {   // diagonal band: per-element LUT bias
            #pragma unroll
            for (int rg = 0; rg < 2; ++rg) {
                const int d0 = i_lo + rg * 16 + t16 - keybase - quad * 4;
                #pragma unroll
                for (int nb = 0; nb < 2; ++nb) {
                    #pragma unroll
                    for (int r = 0; r < 4; ++r) {
                        int d = d0 - nb * 16 - r;
                        d = d < 0 ? 0 : (d > 255 ? 255 : d);
                        sa[rg][nb][r] += lut[d];
                    }
                }
            }
        }
        if (domask && (len & 63)) {   // key-padding, boundary tile only
            #pragma unroll
            for (int nb = 0; nb < 2; ++nb) {
                #pragma unroll
                for (int r = 0; r < 4; ++r) {
                    bool valid = (keybase + nb * 16 + quad * 4 + r) < len;
                    #pragma unroll
                    for (int rg = 0; rg < 2; ++rg)
                        sa[rg][nb][r] = valid ? sa[rg][nb][r] : -1e30f;
                }
            }
        }
        #pragma unroll
        for (int rg = 0; rg < 2; ++rg) {
            float ssum = 0.f;
            #pragma unroll
            for (int nb = 0; nb < 2; ++nb)
                #pragma unroll
                for (int r = 0; r < 4; ++r) {
                    sa[rg][nb][r] = EXP2F(sa[rg][nb][r]);
                    ssum += sa[rg][nb][r];
                }
            l_[rg] += ssum;
        }
    };
    auto pv_tile = [&](const floatx4 (&sa)[2][2], const half4 (&bv)[4][2]) {
        half4 aA0 = pack4(sa[0][0]);
        half4 aB0 = pack4(sa[0][1]);
        half4 aA1 = pack4(sa[1][0]);
        half4 aB1 = pack4(sa[1][1]);
        __builtin_amdgcn_s_setprio(1);
        #pragma unroll
        for (int nb = 0; nb < 4; ++nb) {
            acc[0][nb] = __builtin_amdgcn_mfma_f32_16x16x16f16(aA0, bv[nb][0], acc[0][nb], 0, 0, 0);
            acc[0][nb] = __builtin_amdgcn_mfma_f32_16x16x16f16(aB0, bv[nb][1], acc[0][nb], 0, 0, 0);
            acc[1][nb] = __builtin_amdgcn_mfma_f32_16x16x16f16(aA1, bv[nb][0], acc[1][nb], 0, 0, 0);
            acc[1][nb] = __builtin_amdgcn_mfma_f32_16x16x16f16(aB1, bv[nb][1], acc[1][nb], 0, 0, 0);
        }
        __builtin_amdgcn_s_setprio(0);
    };

    // ---- prologue: tiles 0,1 staged; tiles 2,3 in flight
    prefetchA(0); prefetchB(1);
    stageA(); stageB();
    prefetchA(2); prefetchB(3);
    __syncthreads();

    // ---- main loop: 2 tiles per iteration (ILP-2), 2 barriers per pair
    for (int kt = 0; kt + 1 < ntiles; kt += 2) {
        const int kb0 = kt * BK + kh * 32;
        const int kb1 = kb0 + BK;
        const bool un0 = (i_lo + 31 <= kb0), uf0 = (i_lo >= kb0 + 247);
        const bool un1 = (i_lo + 31 <= kb1), uf1 = (i_lo >= kb1 + 247);
        const float c0 = un0 ? -sh_next : (uf0 ? -sh_far : 0.f);
        const float c1 = un1 ? -sh_next : (uf1 ? -sh_far : 0.f);
        const floatx4 ci0 = {c0, c0, c0, c0};
        const floatx4 ci1 = {c1, c1, c1, c1};

        // QK for both tiles back-to-back: two independent MFMA chains
        floatx4 saA[2][2], saB[2][2];
        qk_tile(0,    ci0, saA);
        qk_tile(4096, ci1, saB);

        half4 bv[4][2];
        vload(0, bv);                               // t0's V; hides under exp(t0)
        bias_exp(kb0, un0, uf0, false, saA);        // kt <= ntiles-2: never masked
        pv_tile(saA, bv);

        vload(4096, bv);                            // t1's V; hides under PV(t0)
        bias_exp(kb1, un1, uf1, (kt + 2 >= ntiles), saB);
        pv_tile(saB, bv);

        __syncthreads();                            // all reads of buf0/buf1 done
        if (kt + 2 < ntiles) {
            stageA(); stageB();                     // vmcnt slack: one full pair
            prefetchA(kt + 4); prefetchB(kt + 5);
            __syncthreads();                        // writes visible for next pair
        }
    }

    // ---- odd tail: single tile (even index -> buf0), includes mask
    if (ntiles & 1) {
        const int ktl = ntiles - 1;
        const int kb0 = ktl * BK + kh * 32;
        const bool un0 = (i_lo + 31 <= kb0), uf0 = (i_lo >= kb0 + 247);
        const float c0 = un0 ? -sh_next : (uf0 ? -sh_far : 0.f);
        const floatx4 ci0 = {c0, c0, c0, c0};
        floatx4 saA[2][2];
        qk_tile(0, ci0, saA);
        half4 bv[4][2];
        vload(0, bv);
        bias_exp(kb0, un0, uf0, true, saA);
        pv_tile(saA, bv);
    }
    __syncthreads();   // all LDS reads done before epilogue reuses the region

    // ---- epilogue: combine the kh pair's additive partials (exact: fixed-shift
    // softmax has no running max), then normalize and store.
    float lh[2];
    #pragma unroll
    for (int rg = 0; rg < 2; ++rg) {
        float lv = l_[rg];
        lv += __shfl_xor(lv, 16, 64);
        lv += __shfl_xor(lv, 32, 64);
        lh[rg] = lv;  // row-sum over this wave's keys, replicated across quads
    }
    // K/V tiles are dead now -> reuse as scratch
    float* Ox = reinterpret_cast<float*>(smem);           // [128][OX_STR]
    float* Lx = reinterpret_cast<float*>(smem + LX_OFF);  // [128]
    if (kh == 1) {
        #pragma unroll
        for (int rg = 0; rg < 2; ++rg) {
            #pragma unroll
            for (int nb = 0; nb < 4; ++nb)
                #pragma unroll
                for (int r = 0; r < 4; ++r)
                    Ox[(wq * 32 + rg * 16 + quad * 4 + r) * OX_STR + nb * 16 + t16] =
                        acc[rg][nb][r];
            if (quad == 0) Lx[wq * 32 + rg * 16 + t16] = lh[rg];
        }
    }
    __syncthreads();
    if (kh == 0) {
        #pragma unroll
        for (int rg = 0; rg < 2; ++rg) {
            const float inv = 1.f / (lh[rg] + Lx[wq * 32 + rg * 16 + t16]);
            #pragma unroll
            for (int r = 0; r < 4; ++r) {
                const int rowloc = quad * 4 + r;  // local row this lane's acc holds
                const float invr = __shfl(inv, (lane & 48) | rowloc, 64);
                const int row = qblk * BQ + wq * 32 + rg * 16 + rowloc;
                #pragma unroll
                for (int nb = 0; nb < 4; ++nb)
                    optr[(size_t)row * D_ + nb * 16 + t16] =
                        (acc[rg][nb][r] +
                         Ox[(wq * 32 + rg * 16 + rowloc) * OX_STR + nb * 16 + t16]) * invr;
            }
        }
    }
}

extern "C" void kernel_launch(void* const* d_in, const int* in_sizes, int n_in,
                              void* d_out, int out_size, void* d_ws, size_t ws_size,
                              hipStream_t stream) {
    const float* q  = (const float*)d_in[0];
    const float* k  = (const float*)d_in[1];
    const float* v  = (const float*)d_in[2];
    const float* bt = (const float*)d_in[3];
    const int*   el = (const int*)d_in[4];
    float* out = (float*)d_out;
    dim3 grid(NQB, H_, B_);
    t5_attn_kernel<<<grid, 512, 0, stream>>>(q, k, v, bt, el, out);
}

// Round 7
// 123.333 us; speedup vs baseline: 2.6996x; 2.6996x over previous
//
#include <hip/hip_runtime.h>

#define B_ 2
#define H_ 16
#define S_ 2048
#define D_ 64
#define BQ 128     // q-rows per block: 8 waves = 4 row-groups x 2 key-halves
#define BK 64
#define NQB (S_ / BQ)   // 16 q-blocks per (b,h)
#define NKT (S_ / BK)   // 32 key tiles max
#define LDSH 64    // halfs per LDS row (128B); 16B chunks XOR-swizzled by row&7
#define NBUF 3     // tri-buffer: single barrier per tile
#define LOG2E 1.4426950408889634f
#define FIXM 10.0f // fixed softmax shift (log2 domain); cancels exactly in O = PV/l

#if __has_builtin(__builtin_amdgcn_exp2f)
#define EXP2F(x) __builtin_amdgcn_exp2f(x)
#else
#define EXP2F(x) __expf((x) * 0.6931471805599453f)
#endif

typedef _Float16 half8 __attribute__((ext_vector_type(8)));
typedef _Float16 half4 __attribute__((ext_vector_type(4)));
typedef __fp16   fp16x2 __attribute__((ext_vector_type(2)));  // cvt_pkrtz return type
typedef float floatx4 __attribute__((ext_vector_type(4)));

// LDS carve (bytes):
//   KL [3][64][64] half @ 0      (24576)   logical [buf][key][dim]
//   VT [3][64][64] half @ 24576  (24576)   logical [buf][dim][key]
//   lut [256] float @ 49152      (1024)
// Total 50176 -> 2 blocks/CU (100 KB of 160 KB). Epilogue reuses [0,34304)
// as fp32 scratch: Ox[128][66] @0, Lx[128] @33792.
#define VT_OFF  24576
#define LUT_OFF 49152
#define OX_STR  66
#define LX_OFF  33792
#define SMEM_BYTES 50176

__global__ __launch_bounds__(512, 4)
void t5_attn_kernel(const float* __restrict__ qg_, const float* __restrict__ kg_,
                    const float* __restrict__ vg_, const float* __restrict__ bt,
                    const int* __restrict__ elen, float* __restrict__ outg_)
{
    __shared__ __align__(16) unsigned char smem[SMEM_BYTES];
    _Float16* KL = reinterpret_cast<_Float16*>(smem);            // [3][4096]
    _Float16* VT = reinterpret_cast<_Float16*>(smem + VT_OFF);   // [3][4096]
    float*   lut = reinterpret_cast<float*>(smem + LUT_OFF);     // [256]

    const int tid  = threadIdx.x;
    const int wave = tid >> 6;
    const int lane = tid & 63;
    const int quad = lane >> 4;
    const int t16  = lane & 15;
    const int t8   = t16 & 7;    // row parity for the chunk XOR swizzle
    const int wq   = wave >> 1;  // 0..3: q row-group (32 rows)
    const int kh   = wave & 1;   // 0/1: key half (32 keys) of each 64-key tile

    // XCD-aware remap (verified FETCH 100->20MB): all 16 q-blocks of one (b,h)
    // land on one XCD; b alternates in bit 3 for CU load mixing.
    const int f    = blockIdx.x + NQB * (blockIdx.y + H_ * blockIdx.z);
    const int qblk = (f >> 3) & 15;
    const int bh   = (f & 7) | ((f >> 7) << 3);
    const int h    = bh & 15;
    const int b    = bh >> 4;

    // ---- bias LUT with FIXM folded in: lut[n] = bt[bucket(n)][h]*log2e - FIXM
    if (tid < 256) {
        int n = tid;
        int bucket;
        if (n < 16) {
            bucket = n;
        } else {
            int vl = (int)(__log2f((float)n * 0.0625f) * 4.0f);
            bucket = 16 + (vl < 15 ? vl : 15);
        }
        lut[n] = bt[bucket * H_ + h] * LOG2E - FIXM;
    }
    // uniform-tile shifts: arg = sa - sh, sh = FIXM - bias*log2e
    const float sh_next = FIXM - bt[h] * LOG2E;           // all d<=0 (bucket 0)
    const float sh_far  = FIXM - bt[31 * H_ + h] * LOG2E; // all d>=216 (bucket 31)

    // robust event_length read (int32 vs int64 layouts; valid lengths >= 1)
    const int len = (elen[1] == 0) ? elen[2 * b] : elen[b];
    const int ntiles = (len + BK - 1) >> 6;  // keys beyond len give exp()=0 exactly

    const size_t bhoff = ((size_t)b * H_ + h) * (size_t)(S_ * D_);
    const float* qptr = qg_ + bhoff;
    const float* kptr = kg_ + bhoff;
    const float* vptr = vg_ + bhoff;
    float*       optr = outg_ + bhoff;

    // ---- Q fragments: 2 row-groups x 2 k-chunks, scaled by (1/8)*log2e.
    // Built in A-layout; used in the B slot (A/B lane-mappings coincide for
    // 16x16x32), so QK^T computes S^T = K.Q^T: C row=key, col=qrow.
    half8 qf[2][2];
    {
        const float qscale = 0.125f * LOG2E;
        #pragma unroll
        for (int rg = 0; rg < 2; ++rg) {
            const int row = qblk * BQ + wq * 32 + rg * 16 + t16;
            const float* qp = qptr + (size_t)row * D_ + quad * 8;
            #pragma unroll
            for (int c = 0; c < 2; ++c) {
                const float4* pq = reinterpret_cast<const float4*>(qp + c * 32);
                float4 x0 = pq[0], x1 = pq[1];
                half8 hv;
                hv[0] = (_Float16)(x0.x * qscale); hv[1] = (_Float16)(x0.y * qscale);
                hv[2] = (_Float16)(x0.z * qscale); hv[3] = (_Float16)(x0.w * qscale);
                hv[4] = (_Float16)(x1.x * qscale); hv[5] = (_Float16)(x1.y * qscale);
                hv[6] = (_Float16)(x1.z * qscale); hv[7] = (_Float16)(x1.w * qscale);
                qf[rg][c] = hv;
            }
        }
    }

    floatx4 acc[2][4];         // acc[rg][nb][r]: qrow rg*16+quad*4+r, dim nb*16+t16
    float l_[2];               // per-lane partial row-sum (this wave's key-half)
    #pragma unroll
    for (int rg = 0; rg < 2; ++rg) {
        #pragma unroll
        for (int nb = 0; nb < 4; ++nb) acc[rg][nb] = floatx4{0.f, 0.f, 0.f, 0.f};
        l_[rg] = 0.f;
    }

    const int i_lo = qblk * BQ + wq * 32;  // first q-row this wave owns

    // pack 4 fp32 -> half4 (RTZ, matches previous P path rounding)
    auto pack4 = [](const floatx4& v) -> half4 {
        fp16x2 lo = __builtin_amdgcn_cvt_pkrtz(v[0], v[1]);
        fp16x2 hi = __builtin_amdgcn_cvt_pkrtz(v[2], v[3]);
        half4 w;
        w[0] = (_Float16)lo[0]; w[1] = (_Float16)lo[1];
        w[2] = (_Float16)hi[0]; w[3] = (_Float16)hi[1];
        return w;
    };

    // ---- staging geometry (tile-invariant); ONE staging register set
    const int krow = tid >> 3;                                       // K row staged
    const int kst  = krow * LDSH + (((tid & 7) ^ (krow & 7)) << 3);  // swizzled
    const int vst  = lane * LDSH + ((wave ^ (lane & 7)) << 3);       // swizzled
    const int c8w  = (tid & 7) << 3;

    float4 kx0, kx1;
    float  vx[8];
    auto prefetch = [&](int kt) {   // tile kt -> regs (clamped; beyond-len never computed)
        const int ktc = kt < NKT ? kt : NKT - 1;
        const float4* pp = reinterpret_cast<const float4*>(
            kptr + (size_t)(ktc * BK + krow) * D_ + c8w);
        kx0 = pp[0];
        kx1 = pp[1];
        const float* vb = vptr + (size_t)(ktc * BK + wave * 8) * D_ + lane;
        #pragma unroll
        for (int jj = 0; jj < 8; ++jj)
            vx[jj] = vb[jj * D_];
    };
    auto stage = [&](int bufe) {    // regs -> LDS buffer (element base bufe)
        half8 hv;
        hv[0]=(_Float16)kx0.x; hv[1]=(_Float16)kx0.y; hv[2]=(_Float16)kx0.z; hv[3]=(_Float16)kx0.w;
        hv[4]=(_Float16)kx1.x; hv[5]=(_Float16)kx1.y; hv[6]=(_Float16)kx1.z; hv[7]=(_Float16)kx1.w;
        *reinterpret_cast<half8*>(KL + bufe + kst) = hv;
        half8 vv;
        #pragma unroll
        for (int jj = 0; jj < 8; ++jj) vv[jj] = (_Float16)vx[jj];
        *reinterpret_cast<half8*>(VT + bufe + vst) = vv;
    };

    // ---- prologue: buf0 <- tile0; regs <- tile1
    prefetch(0);
    stage(0);
    prefetch(1);
    __syncthreads();

    // ---- main loop: ONE barrier per tile.
    // Region t: stage(buf[(t+1)%3]) [no reader this region] || prefetch(t+2)
    //           || compute(buf[t%3]). Buffer (t+1)%3's previous reader was
    //           region t-2 (two barriers back) -> tri-buffer is safe.
    int cur = 0;
    for (int kt = 0; kt < ntiles; ++kt) {
        const int nxt  = (cur + 1 == NBUF) ? 0 : cur + 1;
        const int curb = cur * 4096;
        const int nxtb = nxt * 4096;

        stage(nxtb);        // tile kt+1 (regs) -> LDS; overlaps with compute below
        prefetch(kt + 2);   // global loads issued; ~1.5 tiles of vmcnt slack

        const int keybase = kt * BK + kh * 32;  // this wave's 32 keys

        // ---- wave-uniform bias classification: fold uniform shift into C-init
        const bool unif_next = (i_lo + 31 <= keybase);       // all d<=0 -> bucket 0
        const bool unif_far  = (i_lo >= keybase + 247);      // all d>=216 -> bucket 31
        const float cinit = unif_next ? -sh_next : (unif_far ? -sh_far : 0.f);
        const floatx4 ci = {cinit, cinit, cinit, cinit};

        // ---- S^T = K (Q*log2e/8)^T : row=key (quad*4+r), col=qrow (t16)
        floatx4 sa[2][2];
        #pragma unroll
        for (int rg = 0; rg < 2; ++rg)
            #pragma unroll
            for (int nb = 0; nb < 2; ++nb) sa[rg][nb] = ci;
        __builtin_amdgcn_s_setprio(1);
        #pragma unroll
        for (int kc = 0; kc < 2; ++kc) {
            #pragma unroll
            for (int nb = 0; nb < 2; ++nb) {
                // swizzled K read: logical chunk (kc*4+quad) ^ (row&7 = t8)
                half8 af = *reinterpret_cast<const half8*>(
                    KL + curb + (kh * 32 + nb * 16 + t16) * LDSH +
                    ((((kc << 2) | quad) ^ t8) << 3));
                sa[0][nb] = __builtin_amdgcn_mfma_f32_16x16x32_f16(af, qf[0][kc], sa[0][nb], 0, 0, 0);
                sa[1][nb] = __builtin_amdgcn_mfma_f32_16x16x32_f16(af, qf[1][kc], sa[1][nb], 0, 0, 0);
            }
        }
        __builtin_amdgcn_s_setprio(0);

        // ---- issue V reads NOW: independent of sa, latency hides under exp2.
        half4 bvv[4][2];
        #pragma unroll
        for (int nb = 0; nb < 4; ++nb) {
            #pragma unroll
            for (int s = 0; s < 2; ++s) {
                bvv[nb][s] = *reinterpret_cast<const half4*>(
                    VT + curb + (nb * 16 + t16) * LDSH +
                    ((((kh << 2) | (s << 1) | (quad >> 1)) ^ t8) << 3) +
                    ((quad & 1) << 2));
            }
        }

        // ---- LUT bias only on the (few) diagonal tiles
        if (!unif_next && !unif_far) {
            #pragma unroll
            for (int rg = 0; rg < 2; ++rg) {
                // d = qrow - key = (i_lo+rg*16+t16) - (keybase+nb*16+quad*4+r)
                const int d0 = i_lo + rg * 16 + t16 - keybase - quad * 4;
                #pragma unroll
                for (int nb = 0; nb < 2; ++nb) {
                    #pragma unroll
                    for (int r = 0; r < 4; ++r) {
                        int d = d0 - nb * 16 - r;
                        d = d < 0 ? 0 : (d > 255 ? 255 : d);
                        sa[rg][nb][r] += lut[d];
                    }
                }
            }
        }
        // key-padding mask: only the (block-uniform) boundary tile needs it
        if ((kt == ntiles - 1) && (len & 63)) {
            #pragma unroll
            for (int nb = 0; nb < 2; ++nb) {
                #pragma unroll
                for (int r = 0; r < 4; ++r) {
                    bool valid = (keybase + nb * 16 + quad * 4 + r) < len;
                    #pragma unroll
                    for (int rg = 0; rg < 2; ++rg)
                        sa[rg][nb][r] = valid ? sa[rg][nb][r] : -1e30f;
                }
            }
        }

        // ---- fixed-shift softmax + partial l (no max, no rescale, no shuffles)
        #pragma unroll
        for (int rg = 0; rg < 2; ++rg) {
            float ssum = 0.f;
            #pragma unroll
            for (int nb = 0; nb < 2; ++nb)
                #pragma unroll
                for (int r = 0; r < 4; ++r) {
                    sa[rg][nb][r] = EXP2F(sa[rg][nb][r]);
                    ssum += sa[rg][nb][r];
                }
            l_[rg] += ssum;
        }

        // ---- O += P V, P in registers (16x16x16: A-operand = S^T C-layout)
        {
            half4 aA0 = pack4(sa[0][0]);  // rg0, keys kh*32 + quad*4+[0..3]
            half4 aB0 = pack4(sa[0][1]);  // rg0, keys kh*32+16 + quad*4+[0..3]
            half4 aA1 = pack4(sa[1][0]);  // rg1, low slice
            half4 aB1 = pack4(sa[1][1]);  // rg1, high slice
            __builtin_amdgcn_s_setprio(1);
            #pragma unroll
            for (int nb = 0; nb < 4; ++nb) {
                acc[0][nb] = __builtin_amdgcn_mfma_f32_16x16x16f16(aA0, bvv[nb][0], acc[0][nb], 0, 0, 0);
                acc[0][nb] = __builtin_amdgcn_mfma_f32_16x16x16f16(aB0, bvv[nb][1], acc[0][nb], 0, 0, 0);
                acc[1][nb] = __builtin_amdgcn_mfma_f32_16x16x16f16(aA1, bvv[nb][0], acc[1][nb], 0, 0, 0);
                acc[1][nb] = __builtin_amdgcn_mfma_f32_16x16x16f16(aB1, bvv[nb][1], acc[1][nb], 0, 0, 0);
            }
            __builtin_amdgcn_s_setprio(0);
        }

        __syncthreads();   // single barrier: stage(nxt) visible; buf rotation safe
        cur = nxt;
    }

    // ---- epilogue: combine the kh pair's additive partials (exact: fixed-shift
    // softmax has no running max), then normalize and store.
    float lh[2];
    #pragma unroll
    for (int rg = 0; rg < 2; ++rg) {
        float lv = l_[rg];
        lv += __shfl_xor(lv, 16, 64);
        lv += __shfl_xor(lv, 32, 64);
        lh[rg] = lv;  // row-sum over this wave's keys, replicated across quads
    }
    // K/V tiles are dead past the loop's final barrier -> reuse as scratch
    float* Ox = reinterpret_cast<float*>(smem);           // [128][OX_STR]
    float* Lx = reinterpret_cast<float*>(smem + LX_OFF);  // [128]
    if (kh == 1) {
        #pragma unroll
        for (int rg = 0; rg < 2; ++rg) {
            #pragma unroll
            for (int nb = 0; nb < 4; ++nb)
                #pragma unroll
                for (int r = 0; r < 4; ++r)
                    Ox[(wq * 32 + rg * 16 + quad * 4 + r) * OX_STR + nb * 16 + t16] =
                        acc[rg][nb][r];
            if (quad == 0) Lx[wq * 32 + rg * 16 + t16] = lh[rg];
        }
    }
    __syncthreads();
    if (kh == 0) {
        #pragma unroll
        for (int rg = 0; rg < 2; ++rg) {
            const float inv = 1.f / (lh[rg] + Lx[wq * 32 + rg * 16 + t16]);
            #pragma unroll
            for (int r = 0; r < 4; ++r) {
                const int rowloc = quad * 4 + r;  // local row this lane's acc holds
                const float invr = __shfl(inv, (lane & 48) | rowloc, 64);
                const int row = qblk * BQ + wq * 32 + rg * 16 + rowloc;
                #pragma unroll
                for (int nb = 0; nb < 4; ++nb)
                    optr[(size_t)row * D_ + nb * 16 + t16] =
                        (acc[rg][nb][r] +
                         Ox[(wq * 32 + rg * 16 + rowloc) * OX_STR + nb * 16 + t16]) * invr;
            }
        }
    }
}

extern "C" void kernel_launch(void* const* d_in, const int* in_sizes, int n_in,
                              void* d_out, int out_size, void* d_ws, size_t ws_size,
                              hipStream_t stream) {
    const float* q  = (const float*)d_in[0];
    const float* k  = (const float*)d_in[1];
    const float* v  = (const float*)d_in[2];
    const float* bt = (const float*)d_in[3];
    const int*   el = (const int*)d_in[4];
    float* out = (float*)d_out;
    dim3 grid(NQB, H_, B_);
    t5_attn_kernel<<<grid, 512, 0, stream>>>(q, k, v, bt, el, out);
}